// Round 1
// baseline (1763.649 us; speedup 1.0000x reference)
//
#include <hip/hip_runtime.h>
#include <stdint.h>

#define DEV __device__ __forceinline__

typedef __bf16 bf16x8 __attribute__((ext_vector_type(8)));
typedef float  f32x4  __attribute__((ext_vector_type(4)));

static constexpr int LDW = 72;   // padded LDS row stride (bf16 elems) for 64-wide K tiles

// ---- model dims ----
// B=128, SEQ=1024, ENC=64, D=512, SEG=64, SNX=16, PRED=512, SNY=8
// N_enc = B*ENC = 8192 rows; N_dec = B*ENC*SNY = 65536 rows

DEV unsigned short f2bf(float f){
  union { float f; uint32_t u; } v; v.f = f;
  uint32_t r = (v.u + 0x7FFFu + ((v.u >> 16) & 1u)) >> 16;
  return (unsigned short)r;
}
DEV float bf2f(unsigned short s){
  union { uint32_t u; float f; } v; v.u = ((uint32_t)s) << 16; return v.f;
}
DEV float sigm(float x){ return 1.0f/(1.0f + __expf(-x)); }
DEV float tanhe(float x){ return 1.0f - 2.0f/(__expf(2.0f*x) + 1.0f); }

// stage NROWS x 64 bf16 tile (row-major, ld=ldk elems) into LDS [NROWS][LDW]
template<int NROWS>
DEV void stage_rows(unsigned short* lds, const unsigned short* src, int ldk, int tid){
  #pragma unroll
  for (int i = 0; i < NROWS*8/256; i++){
    int cid = tid + i*256;
    int row = cid >> 3, kc = cid & 7;
    uint4 v = *reinterpret_cast<const uint4*>(src + row*ldk + kc*8);
    *reinterpret_cast<uint4*>(lds + row*LDW + kc*8) = v;
  }
}

// one 64x64 wave tile over a staged 128x64 K-slab: acc += A(128x64-k) * B^T
DEV void mma64(const unsigned short* As, const unsigned short* Bs, int wm0, int wn0,
               int lane, f32x4 acc[4][4]){
  int lr = lane & 15, lk = (lane >> 4)*8;
  #pragma unroll
  for (int ks = 0; ks < 2; ks++){
    int ko = ks*32 + lk;
    bf16x8 a[4], b[4];
    #pragma unroll
    for (int m = 0; m < 4; m++)
      a[m] = *reinterpret_cast<const bf16x8*>(&As[(wm0 + m*16 + lr)*LDW + ko]);
    #pragma unroll
    for (int n = 0; n < 4; n++)
      b[n] = *reinterpret_cast<const bf16x8*>(&Bs[(wn0 + n*16 + lr)*LDW + ko]);
    #pragma unroll
    for (int m = 0; m < 4; m++)
      #pragma unroll
      for (int n = 0; n < 4; n++)
        acc[m][n] = __builtin_amdgcn_mfma_f32_16x16x32_bf16(a[m], b[n], acc[m][n], 0, 0, 0);
  }
}

// K-loop helper: nkt tiles of 64 from A0/B0 (both ld=512), accumulate
DEV void kloop8(const unsigned short* A0, const unsigned short* B0,
                unsigned short* As, unsigned short* Bs, int tid, int wm0, int wn0,
                int lane, f32x4 acc[4][4]){
  for (int kt = 0; kt < 8; kt++){
    stage_rows<128>(As, A0 + kt*64, 512, tid);
    stage_rows<128>(Bs, B0 + kt*64, 512, tid);
    __syncthreads();
    mma64(As, Bs, wm0, wn0, lane, acc);
    __syncthreads();
  }
}

// ---------------- small utility kernels ----------------
__global__ __launch_bounds__(256) void cvt_bf16_kernel(const float* s, unsigned short* d, int n){
  int i = blockIdx.x*256 + threadIdx.x;
  if (i < n) d[i] = f2bf(s[i]);
}

__global__ __launch_bounds__(256) void build_pe_kernel(const float* pos, const float* chan, unsigned short* pe){
  // pe: 512 rows (m = c*8+sy) x 512 cols: [0:256)=pos_emb[sy], [256:512)=channel_emb[c]
  int i = blockIdx.x*256 + threadIdx.x;   // 262144 total
  if (i >= 512*512) return;
  int m = i >> 9, d = i & 511;
  int c = m >> 3, sy = m & 7;
  float v = (d < 256) ? pos[sy*256 + d] : chan[c*256 + (d-256)];
  pe[i] = f2bf(v);
}

// ---------------- embedding: emb_t = silu(xs_t @ W_emb^T + b_emb) ----------------
__global__ __launch_bounds__(256) void embed_kernel(const float* __restrict__ x,
    const unsigned short* __restrict__ Wemb, const float* __restrict__ b_emb,
    unsigned short* __restrict__ embt, int t){
  __shared__ unsigned short As[128*LDW];
  __shared__ unsigned short Bs[128*LDW];
  int tid = threadIdx.x, lane = tid & 63, wid = tid >> 6;
  int wm0 = (wid >> 1)*64, wn0 = (wid & 1)*64;
  int rA0 = blockIdx.x*128, d0 = blockIdx.y*128;

  // build A tile (xs rows) on the fly: xs[n,k] = x[b, t*64+k, c] - x[b,1023,c]
  {
    int row = tid & 127;
    int khalf = tid >> 7;            // 0 or 1
    int n = rA0 + row, b = n >> 6, c = n & 63;
    const float* xb = x + b*65536 + c;
    float last = xb[65472];          // x[b,1023,c]
    #pragma unroll
    for (int i = 0; i < 32; i++){
      int k = khalf + i*2;
      As[row*LDW + k] = f2bf(xb[(t*64 + k)*64] - last);
    }
  }
  stage_rows<128>(Bs, Wemb + d0*64, 64, tid);
  __syncthreads();

  f32x4 z4 = {0.f,0.f,0.f,0.f};
  f32x4 acc[4][4];
  #pragma unroll
  for (int m = 0; m < 4; m++)
    #pragma unroll
    for (int n = 0; n < 4; n++) acc[m][n] = z4;
  mma64(As, Bs, wm0, wn0, lane, acc);   // K = 64 exactly

  int lr = lane & 15, lj = (lane >> 4)*4;
  #pragma unroll
  for (int m = 0; m < 4; m++)
    #pragma unroll
    for (int n = 0; n < 4; n++)
      #pragma unroll
      for (int j = 0; j < 4; j++){
        int row = rA0 + wm0 + m*16 + lj + j;
        int col = d0 + wn0 + n*16 + lr;
        float v = acc[m][n][j] + b_emb[col];
        v = v * sigm(v);              // SiLU
        embt[row*512 + col] = f2bf(v);
      }
}

// ---------------- encoder GRU cell gates -> h_cell ----------------
__global__ __launch_bounds__(256) void gates_kernel(
    const unsigned short* __restrict__ embt, const unsigned short* __restrict__ hbf,
    const float* __restrict__ hf32,
    const unsigned short* __restrict__ Wih, const unsigned short* __restrict__ Whh,
    const float* __restrict__ bih, const float* __restrict__ bhh,
    unsigned short* __restrict__ hcell){
  __shared__ unsigned short As[128*LDW];
  __shared__ unsigned short Bs[128*LDW];
  int tid = threadIdx.x, lane = tid & 63, wid = tid >> 6;
  int wm0 = (wid >> 1)*64, wn0 = (wid & 1)*64;
  int rA0 = blockIdx.x*128, d0 = blockIdx.y*128;
  const unsigned short* Aemb = embt + rA0*512;
  const unsigned short* Ah   = hbf  + rA0*512;

  f32x4 z4 = {0.f,0.f,0.f,0.f};
  f32x4 accR[4][4], accX[4][4], accT[4][4];
  #pragma unroll
  for (int m = 0; m < 4; m++)
    #pragma unroll
    for (int n = 0; n < 4; n++){ accR[m][n] = z4; accX[m][n] = z4; accT[m][n] = z4; }

  // phase R: xr+hr  (K=1024 virtual concat), gate rows d0+0
  kloop8(Aemb, Wih + (0    + d0)*512, As, Bs, tid, wm0, wn0, lane, accR);
  kloop8(Ah,   Whh + (0    + d0)*512, As, Bs, tid, wm0, wn0, lane, accR);
  // phase X: xn (K=512), gate rows 1024+d0
  kloop8(Aemb, Wih + (1024 + d0)*512, As, Bs, tid, wm0, wn0, lane, accX);
  // phase T: hn (K=512)
  kloop8(Ah,   Whh + (1024 + d0)*512, As, Bs, tid, wm0, wn0, lane, accT);

  int lr = lane & 15, lj = (lane >> 4)*4;
  // ng = tanh(xn + rg*hn) -> store into accX; free accR/accT
  #pragma unroll
  for (int m = 0; m < 4; m++)
    #pragma unroll
    for (int n = 0; n < 4; n++){
      int col = d0 + wn0 + n*16 + lr;
      float b_r_i = bih[col],        b_r_h = bhh[col];
      float b_n_i = bih[1024 + col], b_n_h = bhh[1024 + col];
      #pragma unroll
      for (int j = 0; j < 4; j++){
        float rg = sigm(accR[m][n][j] + b_r_i + b_r_h);
        float hn = accT[m][n][j] + b_n_h;
        float xn = accX[m][n][j] + b_n_i;
        accX[m][n][j] = tanhe(xn + rg*hn);
        accT[m][n][j] = 0.f;
      }
    }
  __syncthreads();

  // phase Z: xz+hz (K=1024), gate rows 512+d0 -> accT
  kloop8(Aemb, Wih + (512 + d0)*512, As, Bs, tid, wm0, wn0, lane, accT);
  kloop8(Ah,   Whh + (512 + d0)*512, As, Bs, tid, wm0, wn0, lane, accT);

  #pragma unroll
  for (int m = 0; m < 4; m++)
    #pragma unroll
    for (int n = 0; n < 4; n++){
      int col = d0 + wn0 + n*16 + lr;
      float b_z_i = bih[512 + col], b_z_h = bhh[512 + col];
      #pragma unroll
      for (int j = 0; j < 4; j++){
        int row = rA0 + wm0 + m*16 + lj + j;
        float zg = sigm(accT[m][n][j] + b_z_i + b_z_h);
        float h  = hf32[row*512 + col];
        float hc = (1.0f - zg)*accX[m][n][j] + zg*h;
        hcell[row*512 + col] = f2bf(hc);
      }
    }
}

// ---------------- residual projection: h_new = emb_t + h_cell @ res_W^T + res_b ----------------
__global__ __launch_bounds__(256) void res_kernel(
    const unsigned short* __restrict__ hcell, const unsigned short* __restrict__ Wres,
    const float* __restrict__ res_b, const unsigned short* __restrict__ embt,
    float* __restrict__ hf32, unsigned short* __restrict__ hbf){
  __shared__ unsigned short As[128*LDW];
  __shared__ unsigned short Bs[128*LDW];
  int tid = threadIdx.x, lane = tid & 63, wid = tid >> 6;
  int wm0 = (wid >> 1)*64, wn0 = (wid & 1)*64;
  int rA0 = blockIdx.x*128, d0 = blockIdx.y*128;

  f32x4 z4 = {0.f,0.f,0.f,0.f};
  f32x4 acc[4][4];
  #pragma unroll
  for (int m = 0; m < 4; m++)
    #pragma unroll
    for (int n = 0; n < 4; n++) acc[m][n] = z4;

  kloop8(hcell + rA0*512, Wres + d0*512, As, Bs, tid, wm0, wn0, lane, acc);

  int lr = lane & 15, lj = (lane >> 4)*4;
  #pragma unroll
  for (int m = 0; m < 4; m++)
    #pragma unroll
    for (int n = 0; n < 4; n++)
      #pragma unroll
      for (int j = 0; j < 4; j++){
        int row = rA0 + wm0 + m*16 + lj + j;
        int col = d0 + wn0 + n*16 + lr;
        float v = acc[m][n][j] + res_b[col] + bf2f(embt[row*512 + col]);
        hf32[row*512 + col] = v;
        hbf[row*512 + col]  = f2bf(v);
      }
}

// ---------------- generic: C = A(Mx512) @ B^T + bias  (f32 out, ld=1536) ----------------
__global__ __launch_bounds__(256) void gemm_bias_kernel(
    const unsigned short* __restrict__ A, const unsigned short* __restrict__ B,
    const float* __restrict__ bias, float* __restrict__ C, int Nld){
  __shared__ unsigned short As[128*LDW];
  __shared__ unsigned short Bs[128*LDW];
  int tid = threadIdx.x, lane = tid & 63, wid = tid >> 6;
  int wm0 = (wid >> 1)*64, wn0 = (wid & 1)*64;
  int rA0 = blockIdx.x*128, rB0 = blockIdx.y*128;

  f32x4 z4 = {0.f,0.f,0.f,0.f};
  f32x4 acc[4][4];
  #pragma unroll
  for (int m = 0; m < 4; m++)
    #pragma unroll
    for (int n = 0; n < 4; n++) acc[m][n] = z4;

  kloop8(A + rA0*512, B + rB0*512, As, Bs, tid, wm0, wn0, lane, acc);

  int lr = lane & 15, lj = (lane >> 4)*4;
  #pragma unroll
  for (int m = 0; m < 4; m++)
    #pragma unroll
    for (int n = 0; n < 4; n++)
      #pragma unroll
      for (int j = 0; j < 4; j++){
        int row = rA0 + wm0 + m*16 + lj + j;
        int col = rB0 + wn0 + n*16 + lr;
        C[row*Nld + col] = acc[m][n][j] + bias[col];
      }
}

// ---------------- decoder fuse: hy -> y -> out ----------------
__global__ __launch_bounds__(256) void final_kernel(
    const float* __restrict__ gxd, const float* __restrict__ ghd,
    const float* __restrict__ hf32, const unsigned short* __restrict__ predW,
    const float* __restrict__ predb, const float* __restrict__ x, float* __restrict__ out){
  __shared__ unsigned short As[128*LDW];
  __shared__ unsigned short Bs[64*LDW];
  int tid = threadIdx.x, lane = tid & 63, wid = tid >> 6;
  int wm0 = wid*32;                 // 4 waves x (32 rows x 64 cols)
  int r0 = blockIdx.x*128;

  f32x4 z4 = {0.f,0.f,0.f,0.f};
  f32x4 acc[2][4];
  #pragma unroll
  for (int m = 0; m < 2; m++)
    #pragma unroll
    for (int n = 0; n < 4; n++) acc[m][n] = z4;

  for (int kt = 0; kt < 8; kt++){
    int d0 = kt*64;
    // build hy chunk (128 rows x 64 d) elementwise into As
    #pragma unroll 4
    for (int i = 0; i < 32; i++){
      int idx = tid + i*256;
      int dl = idx & 63, rl = idx >> 6;
      int r = r0 + rl;
      int n = r >> 3, sy = r & 7, c = n & 63;
      int mpe = c*8 + sy;
      int d = d0 + dl;
      float xr = gxd[mpe*1536 + d];
      float xz = gxd[mpe*1536 + 512 + d];
      float xn = gxd[mpe*1536 + 1024 + d];
      float hr = ghd[n*1536 + d];
      float hz = ghd[n*1536 + 512 + d];
      float hn = ghd[n*1536 + 1024 + d];
      float rg = sigm(xr + hr);
      float zg = sigm(xz + hz);
      float ng = tanhe(xn + rg*hn);
      float hy = (1.0f - zg)*ng + zg*hf32[n*512 + d];
      As[rl*LDW + dl] = f2bf(hy);
    }
    stage_rows<64>(Bs, predW + d0, 512, tid);
    __syncthreads();

    int lr = lane & 15, lk = (lane >> 4)*8;
    #pragma unroll
    for (int ks = 0; ks < 2; ks++){
      int ko = ks*32 + lk;
      bf16x8 a[2], b[4];
      #pragma unroll
      for (int m = 0; m < 2; m++)
        a[m] = *reinterpret_cast<const bf16x8*>(&As[(wm0 + m*16 + lr)*LDW + ko]);
      #pragma unroll
      for (int n = 0; n < 4; n++)
        b[n] = *reinterpret_cast<const bf16x8*>(&Bs[(n*16 + lr)*LDW + ko]);
      #pragma unroll
      for (int m = 0; m < 2; m++)
        #pragma unroll
        for (int n = 0; n < 4; n++)
          acc[m][n] = __builtin_amdgcn_mfma_f32_16x16x32_bf16(a[m], b[n], acc[m][n], 0, 0, 0);
    }
    __syncthreads();
  }

  int lr = lane & 15, lj = (lane >> 4)*4;
  #pragma unroll
  for (int m = 0; m < 2; m++)
    #pragma unroll
    for (int n = 0; n < 4; n++){
      int s = n*16 + lr;
      float bb = predb[s];
      #pragma unroll
      for (int j = 0; j < 4; j++){
        int rl = wm0 + m*16 + lj + j;
        int r = r0 + rl;
        int nn = r >> 3, sy = r & 7;
        int b = nn >> 6, c = nn & 63;
        float y = acc[m][n][j] + bb + x[b*65536 + 65472 + c];
        out[b*32768 + (sy*64 + s)*64 + c] = y;
      }
    }
}

// ---------------- host ----------------
extern "C" void kernel_launch(void* const* d_in, const int* in_sizes, int n_in,
                              void* d_out, int out_size, void* d_ws, size_t ws_size,
                              hipStream_t stream){
  (void)in_sizes; (void)n_in; (void)out_size; (void)ws_size;
  const float* x     = (const float*)d_in[0];
  const float* Wemb  = (const float*)d_in[1];
  const float* bemb  = (const float*)d_in[2];
  const float* cWih  = (const float*)d_in[3];
  const float* cWhh  = (const float*)d_in[4];
  const float* cbih  = (const float*)d_in[5];
  const float* cbhh  = (const float*)d_in[6];
  const float* gWih  = (const float*)d_in[7];
  const float* gWhh  = (const float*)d_in[8];
  const float* gbih  = (const float*)d_in[9];
  const float* gbhh  = (const float*)d_in[10];
  const float* resW  = (const float*)d_in[11];
  const float* resb  = (const float*)d_in[12];
  const float* pos   = (const float*)d_in[13];
  const float* chan  = (const float*)d_in[14];
  const float* predW = (const float*)d_in[15];
  const float* predb = (const float*)d_in[16];
  float* out = (float*)d_out;

  uint8_t* ws = (uint8_t*)d_ws;
  size_t o = 0;
  auto take = [&](size_t bytes){ uint8_t* p = ws + o; o += (bytes + 255) & ~(size_t)255; return p; };
  unsigned short* wb_cWih  = (unsigned short*)take(786432*2);
  unsigned short* wb_cWhh  = (unsigned short*)take(786432*2);
  unsigned short* wb_gWih  = (unsigned short*)take(786432*2);
  unsigned short* wb_gWhh  = (unsigned short*)take(786432*2);
  unsigned short* wb_resW  = (unsigned short*)take(262144*2);
  unsigned short* wb_predW = (unsigned short*)take(32768*2);
  unsigned short* wb_Wemb  = (unsigned short*)take(32768*2);
  unsigned short* pe_bf    = (unsigned short*)take(262144*2);
  float*          h_f32    = (float*)take(4194304*4);
  unsigned short* h_bf     = (unsigned short*)take(4194304*2);
  unsigned short* emb_t    = (unsigned short*)take(4194304*2);
  unsigned short* hcell    = (unsigned short*)take(4194304*2);
  float*          gxd      = (float*)take(786432*4);
  float*          ghd      = (float*)take(12582912*4);

  auto cvt = [&](const float* s, unsigned short* d, int n){
    cvt_bf16_kernel<<<(n + 255)/256, 256, 0, stream>>>(s, d, n);
  };
  cvt(cWih,  wb_cWih,  786432);
  cvt(cWhh,  wb_cWhh,  786432);
  cvt(gWih,  wb_gWih,  786432);
  cvt(gWhh,  wb_gWhh,  786432);
  cvt(resW,  wb_resW,  262144);
  cvt(predW, wb_predW, 32768);
  cvt(Wemb,  wb_Wemb,  32768);
  build_pe_kernel<<<(262144 + 255)/256, 256, 0, stream>>>(pos, chan, pe_bf);

  hipMemsetAsync(h_f32, 0, 4194304*4, stream);
  hipMemsetAsync(h_bf,  0, 4194304*2, stream);

  for (int t = 0; t < 16; t++){
    embed_kernel<<<dim3(64, 4), 256, 0, stream>>>(x, wb_Wemb, bemb, emb_t, t);
    gates_kernel<<<dim3(64, 4), 256, 0, stream>>>(emb_t, h_bf, h_f32, wb_cWih, wb_cWhh,
                                                  cbih, cbhh, hcell);
    res_kernel<<<dim3(64, 4), 256, 0, stream>>>(hcell, wb_resW, resb, emb_t, h_f32, h_bf);
  }

  // decoder: ghd = hn @ gru_Whh^T + gbhh ; gxd = pe @ gru_Wih^T + gbih
  gemm_bias_kernel<<<dim3(64, 12), 256, 0, stream>>>(h_bf,  wb_gWhh, gbhh, ghd, 1536);
  gemm_bias_kernel<<<dim3(4, 12),  256, 0, stream>>>(pe_bf, wb_gWih, gbih, gxd, 1536);

  final_kernel<<<512, 256, 0, stream>>>(gxd, ghd, h_f32, wb_predW, predb, x, out);
}